// Round 1
// baseline (457.511 us; speedup 1.0000x reference)
//
#include <hip/hip_runtime.h>
#include <hip/hip_bf16.h>

// Problem constants (from reference): B=8, T=128, U=64, V=1024, blank=V-1.
#define BB 8
#define TT 128
#define UU 64
#define VV 1024
#define U1 65                      // U+1
#define NROWS (BB * TT * U1)       // 66560 log-softmax rows
#define DSZ ((TT + UU) * U1)       // 12480: diagonal-major (d,u) slab per batch

__device__ __forceinline__ float wave_max64(float v) {
#pragma unroll
    for (int off = 32; off; off >>= 1) v = fmaxf(v, __shfl_xor(v, off, 64));
    return v;
}
__device__ __forceinline__ float wave_sum64(float v) {
#pragma unroll
    for (int off = 32; off; off >>= 1) v += __shfl_xor(v, off, 64);
    return v;
}

// Kernel 1: per (b,t,u) row of V=1024 logits, compute logsumexp and emit the
// two surviving log-probs (blank, target) into DIAGONAL-major scratch so the
// DP kernel reads each anti-diagonal contiguously.
// One wave (64 lanes) per row; 4 waves per block.
__global__ __launch_bounds__(256) void rnnt_lse_kernel(
    const float* __restrict__ logits, const int* __restrict__ targets,
    float* __restrict__ bdiag, float* __restrict__ ediag) {
    const int wave = threadIdx.x >> 6;
    const int lane = threadIdx.x & 63;
    const int row  = blockIdx.x * 4 + wave;          // exact: grid*4 == NROWS
    const float* rowp = logits + (size_t)row * VV;
    const float4* p4 = (const float4*)rowp;

    float4 x0 = p4[lane];
    float4 x1 = p4[lane + 64];
    float4 x2 = p4[lane + 128];
    float4 x3 = p4[lane + 192];

    float m = fmaxf(fmaxf(fmaxf(x0.x, x0.y), fmaxf(x0.z, x0.w)),
                    fmaxf(fmaxf(x1.x, x1.y), fmaxf(x1.z, x1.w)));
    m = fmaxf(m, fmaxf(fmaxf(fmaxf(x2.x, x2.y), fmaxf(x2.z, x2.w)),
                       fmaxf(fmaxf(x3.x, x3.y), fmaxf(x3.z, x3.w))));
    m = wave_max64(m);

    float s = __expf(x0.x - m) + __expf(x0.y - m) + __expf(x0.z - m) + __expf(x0.w - m)
            + __expf(x1.x - m) + __expf(x1.y - m) + __expf(x1.z - m) + __expf(x1.w - m)
            + __expf(x2.x - m) + __expf(x2.y - m) + __expf(x2.z - m) + __expf(x2.w - m)
            + __expf(x3.x - m) + __expf(x3.y - m) + __expf(x3.z - m) + __expf(x3.w - m);
    s = wave_sum64(s);

    if (lane == 0) {
        float lse = m + __logf(s);
        int b   = row / (TT * U1);
        int rem = row - b * (TT * U1);
        int t   = rem / U1;
        int u   = rem - t * U1;
        int dpos = (t + u) * U1 + u;                 // diagonal-major position
        bdiag[b * DSZ + dpos] = rowp[VV - 1] - lse;  // L1-hot reload
        if (u < UU) {
            int tgt = targets[b * UU + u];
            ediag[b * DSZ + dpos] = rowp[tgt] - lse;
        }
    }
}

// Kernel 2: anti-diagonal wavefront DP. One block per batch, thread u owns
// column u. alpha kept as two LDS diagonals; blank/emit streamed from global
// (diagonal-major, coalesced) with one-step software prefetch.
__global__ __launch_bounds__(128) void rnnt_dp_kernel(
    const float* __restrict__ bdiag, const float* __restrict__ ediag,
    const int* __restrict__ logit_lengths, const int* __restrict__ target_lengths,
    float* __restrict__ out) {
    const int b = blockIdx.x;
    const int u = threadIdx.x;
    const float* gb = bdiag + b * DSZ;
    const float* ge = ediag + b * DSZ;
    const int tl = logit_lengths[b] - 1;   // in [63,127]
    const int ul = target_lengths[b];      // in [32,64]

    __shared__ float buf0[U1], buf1[U1];
    __shared__ float s_res;
    float* prev = buf0;
    float* cur  = buf1;

    const bool lane_ok = (u <= UU);
    // Prefetch diagonal 0 (consumed at step d=1).
    float bd_n = lane_ok ? gb[u] : 0.f;
    float ed_n = (lane_ok && u >= 1) ? ge[u - 1] : 0.f;

    if (u == 0) cur[0] = 0.f;              // alpha[0][0] = 0
    __syncthreads();
    { float* tmp = prev; prev = cur; cur = tmp; }

    for (int d = 1; d < TT + UU; ++d) {
        float bd = bd_n, ed = ed_n;
        if (d < TT + UU - 1) {             // prefetch diagonal d for step d+1
            bd_n = lane_ok ? gb[d * U1 + u] : 0.f;
            ed_n = (lane_ok && u >= 1) ? ge[d * U1 + u - 1] : 0.f;
        }
        const int t = d - u;
        if (lane_ok && t >= 0 && t < TT) {
            const float NEG = -1e30f;
            // vertical (blank) move from (t-1,u); horizontal (emit) from (t,u-1)
            float va = (t >= 1) ? prev[u]     + bd : NEG;
            float vb = (u >= 1) ? prev[u - 1] + ed : NEG;
            float mm = fmaxf(va, vb);
            float r  = mm + __logf(__expf(va - mm) + __expf(vb - mm));
            cur[u] = r;
            if (t == tl && u == ul) s_res = r;
        }
        __syncthreads();
        { float* tmp = prev; prev = cur; cur = tmp; }
    }

    if (u == 0) out[b] = -(s_res + gb[(tl + ul) * U1 + ul]);
}

extern "C" void kernel_launch(void* const* d_in, const int* in_sizes, int n_in,
                              void* d_out, int out_size, void* d_ws, size_t ws_size,
                              hipStream_t stream) {
    const float* logits         = (const float*)d_in[0];
    const int*   targets        = (const int*)d_in[1];
    const int*   logit_lengths  = (const int*)d_in[2];
    const int*   target_lengths = (const int*)d_in[3];
    float* outp = (float*)d_out;

    float* bdiag = (float*)d_ws;            // B * DSZ floats
    float* ediag = bdiag + (size_t)BB * DSZ; // B * DSZ floats  (total ~800 KB)

    rnnt_lse_kernel<<<NROWS / 4, 256, 0, stream>>>(logits, targets, bdiag, ediag);
    rnnt_dp_kernel<<<BB, 128, 0, stream>>>(bdiag, ediag, logit_lengths,
                                           target_lengths, outp);
}

// Round 2
// 434.667 us; speedup vs baseline: 1.0526x; 1.0526x over previous
//
#include <hip/hip_runtime.h>
#include <hip/hip_bf16.h>

// Problem constants (from reference): B=8, T=128, U=64, V=1024, blank=V-1.
#define BB 8
#define TT 128
#define UU 64
#define VV 1024
#define U1 65                      // U+1
#define NROWS (BB * TT * U1)       // 66560 log-softmax rows
#define NDIAG (TT + UU)            // 192 anti-diagonals
#define DSZ (NDIAG * U1)           // 12480 float2 slots per batch (diag-major)
#define CD 48                      // diagonals per LDS chunk (4 chunks exactly)
#define CH_F4 ((CD * U1) / 2)      // 1560 float4 per chunk (CD*U1=3120 float2)

__device__ __forceinline__ float wave_max64(float v) {
#pragma unroll
    for (int off = 32; off; off >>= 1) v = fmaxf(v, __shfl_xor(v, off, 64));
    return v;
}
__device__ __forceinline__ float wave_sum64(float v) {
#pragma unroll
    for (int off = 32; off; off >>= 1) v += __shfl_xor(v, off, 64);
    return v;
}

// Kernel 1: one wave per (b,t,u) row of V=1024 logits. Computes logsumexp,
// then extracts the two surviving log-probs (blank=last class, target) from
// the already-loaded registers via shuffles, and writes ONE float2 into the
// diagonal-major slab P[b][(t+u)*U1 + u] = {lp_blank, lp_emit}.
__global__ __launch_bounds__(256) void rnnt_lse_kernel(
    const float* __restrict__ logits, const int* __restrict__ targets,
    float2* __restrict__ P) {
    const int wave = threadIdx.x >> 6;
    const int lane = threadIdx.x & 63;
    const int row  = blockIdx.x * 4 + wave;          // grid*4 == NROWS exactly
    const float4* p4 = (const float4*)(logits + (size_t)row * VV);

    float4 x0 = p4[lane];
    float4 x1 = p4[lane + 64];
    float4 x2 = p4[lane + 128];
    float4 x3 = p4[lane + 192];

    float m = fmaxf(fmaxf(fmaxf(x0.x, x0.y), fmaxf(x0.z, x0.w)),
                    fmaxf(fmaxf(x1.x, x1.y), fmaxf(x1.z, x1.w)));
    m = fmaxf(m, fmaxf(fmaxf(fmaxf(x2.x, x2.y), fmaxf(x2.z, x2.w)),
                       fmaxf(fmaxf(x3.x, x3.y), fmaxf(x3.z, x3.w))));
    m = wave_max64(m);

    float s = __expf(x0.x - m) + __expf(x0.y - m) + __expf(x0.z - m) + __expf(x0.w - m)
            + __expf(x1.x - m) + __expf(x1.y - m) + __expf(x1.z - m) + __expf(x1.w - m)
            + __expf(x2.x - m) + __expf(x2.y - m) + __expf(x2.z - m) + __expf(x2.w - m)
            + __expf(x3.x - m) + __expf(x3.y - m) + __expf(x3.z - m) + __expf(x3.w - m);
    s = wave_sum64(s);
    const float lse = m + __logf(s);                 // all lanes hold it

    const int b   = row / (TT * U1);
    const int rem = row - b * (TT * U1);
    const int t   = rem / U1;
    const int u   = rem - t * U1;

    // blank logit = element 1023 = x3.w of lane 63
    const float blankv = __shfl(x3.w, 63, 64) - lse;
    float emitv = 0.f;
    if (u < UU) {                                    // wave-uniform branch
        const int tgt = targets[b * UU + u];         // wave-uniform scalar
        const int q = tgt >> 2, grp = q >> 6, sl = q & 63, c = tgt & 3;
        float4 g4 = (grp == 0) ? x0 : (grp == 1) ? x1 : (grp == 2) ? x2 : x3;
        float cv = (c == 0) ? g4.x : (c == 1) ? g4.y : (c == 2) ? g4.z : g4.w;
        emitv = __shfl(cv, sl, 64) - lse;
    }
    if (lane == 0) P[(size_t)b * DSZ + (t + u) * U1 + u] = make_float2(blankv, emitv);
}

// Kernel 2: anti-diagonal wavefront DP, ONE wave per batch, barrier-free.
// Lane l owns column u=l; lane 63 also owns u=64. alpha diagonal lives in
// registers (neighbor via __shfl_up). blank/emit pairs staged global->LDS in
// 48-diagonal double-buffered chunks, prefetched one chunk ahead into regs.
__global__ __launch_bounds__(64) void rnnt_dp_kernel(
    const float2* __restrict__ P, const int* __restrict__ logit_lengths,
    const int* __restrict__ target_lengths, float* __restrict__ out) {
    const int b = blockIdx.x;
    const int l = threadIdx.x;                       // 0..63
    const float2* Pg = P + (size_t)b * DSZ;
    const int tl = logit_lengths[b] - 1;             // in [63,127]
    const int ul = target_lengths[b];                // in [32,64]

    __shared__ __align__(16) float2 sb[2][CD * U1];  // 49,920 B double buffer

    const float NEG = -1e30f;
    float aprev   = (l == 0) ? 0.f : NEG;            // diag 0: alpha[0][0]=0
    float aprev64 = NEG;                             // lane63's u=64 cell
    float res = 0.f;

    // stage chunk 0 (diagonals 0..47)
    {
        const float4* g4 = (const float4*)Pg;
#pragma unroll
        for (int i = 0; i < 25; ++i) {
            int idx = i * 64 + l;
            if (idx < CH_F4) ((float4*)sb[0])[idx] = g4[idx];
        }
    }

    int d = 1;                                       // current output diagonal
    for (int g = 0; g < 4; ++g) {
        float4 v[25];
        if (g < 3) {                                 // prefetch chunk g+1 -> regs
            const float4* g4 = (const float4*)Pg + (size_t)(g + 1) * CH_F4;
#pragma unroll
            for (int i = 0; i < 25; ++i) {
                int idx = i * 64 + l;
                if (idx < CH_F4) v[i] = g4[idx];
            }
        }
        const float2* buf = sb[g & 1];
#pragma unroll 1
        for (int i = 0; i < CD; ++i, ++d) {
            const int c = g * CD + i;                // consumed diagonal d-1
            if (c > NDIAG - 2) break;                // c max 190
            float2 pr  = buf[i * U1 + l];            // {blank(c,l), emit(c,l)}
            float2 p64 = buf[i * U1 + 64];           // broadcast, col 64
            float edl = __shfl_up(pr.y, 1, 64);      // emit(c, l-1)
            float al  = __shfl_up(aprev, 1, 64);     // alpha[t, l-1]
            const int t = d - l;
            // primary cell (t, u=l)
            float va = (t >= 1) ? aprev + pr.x : NEG;
            float vb = (l >= 1) ? al + edl : NEG;
            float mm = fmaxf(va, vb);
            float r  = mm + __logf(__expf(va - mm) + __expf(vb - mm));
            r = (t >= 0 && t < TT) ? r : NEG;
            // secondary cell (t64, u=64) — meaningful on lane 63 only
            const int t64 = d - 64;
            float va64 = (t64 >= 1) ? aprev64 + p64.x : NEG;
            float vb64 = aprev + pr.y;               // alpha(t64,63)+emit(t64,63)
            float mm64 = fmaxf(va64, vb64);
            float r64  = mm64 + __logf(__expf(va64 - mm64) + __expf(vb64 - mm64));
            r64 = (t64 >= 0) ? r64 : NEG;
            if (d == tl + ul) {
                if (ul < 64) { if (l == ul) res = r; }
                else if (l == 63) res = r64;
            }
            aprev = r; aprev64 = r64;
        }
        if (g < 3) {                                 // regs -> other LDS buffer
            float4* dst = (float4*)sb[(g + 1) & 1];
#pragma unroll
            for (int i = 0; i < 25; ++i) {
                int idx = i * 64 + l;
                if (idx < CH_F4) dst[idx] = v[i];
            }
        }
    }

    const float rr = __shfl(res, (ul < 64) ? ul : 63, 64);
    if (l == 0) out[b] = -(rr + Pg[(tl + ul) * U1 + ul].x);
}

extern "C" void kernel_launch(void* const* d_in, const int* in_sizes, int n_in,
                              void* d_out, int out_size, void* d_ws, size_t ws_size,
                              hipStream_t stream) {
    const float* logits         = (const float*)d_in[0];
    const int*   targets        = (const int*)d_in[1];
    const int*   logit_lengths  = (const int*)d_in[2];
    const int*   target_lengths = (const int*)d_in[3];
    float* outp = (float*)d_out;

    float2* P = (float2*)d_ws;                       // B * DSZ float2 (~800 KB)

    rnnt_lse_kernel<<<NROWS / 4, 256, 0, stream>>>(logits, targets, P);
    rnnt_dp_kernel<<<BB, 64, 0, stream>>>(P, logit_lengths, target_lengths, outp);
}